// Round 4
// baseline (487.471 us; speedup 1.0000x reference)
//
#include <hip/hip_runtime.h>

#define EDGES 1600000
#define NN    100000
#define ZD    64
#define FD    16
#define HID   128
#define BM    32         // edges per tile
#define THREADS 256
#define NBLK  2000       // 2000 blocks x 25 tiles x 32 edges = 1.6M exactly
#define TPB   25

typedef __attribute__((ext_vector_type(8)))  short bfrag;   // 8 bf16 = 4 VGPR
typedef __attribute__((ext_vector_type(16))) float f16v;    // 16 f32 acc

__device__ __forceinline__ unsigned short f2bf(float f) {
  unsigned u = __builtin_bit_cast(unsigned, f);
  u += 0x7fffu + ((u >> 16) & 1u);   // RNE
  return (unsigned short)(u >> 16);
}
__device__ __forceinline__ unsigned cvtpk(float lo, float hi) {
  unsigned r;
  asm("v_cvt_pk_bf16_f32 %0, %1, %2" : "=v"(r) : "v"(lo), "v"(hi));
  return r;
}
__device__ __forceinline__ void gload16(const void* g, void* l) {
  __builtin_amdgcn_global_load_lds(
      (const __attribute__((address_space(1))) unsigned int*)g,
      (__attribute__((address_space(3))) unsigned int*)l, 16, 0, 0);
}

__global__ void zconv_kernel(const float* __restrict__ z,
                             unsigned short* __restrict__ z16, int n4) {
  int i = blockIdx.x * blockDim.x + threadIdx.x;
  if (i >= n4) return;
  float4 f = reinterpret_cast<const float4*>(z)[i];
  ushort4 p;
  p.x = f2bf(f.x); p.y = f2bf(f.y); p.z = f2bf(f.z); p.w = f2bf(f.w);
  reinterpret_cast<ushort4*>(z16)[i] = p;
}

__device__ __forceinline__ bfrag load_wf(const float* __restrict__ W1, int k0, int wcol) {
  const float* p = W1 + (size_t)k0 * HID + wcol;
  int4 q = {(int)cvtpk(p[0],       p[HID]),
            (int)cvtpk(p[2 * HID], p[3 * HID]),
            (int)cvtpk(p[4 * HID], p[5 * HID]),
            (int)cvtpk(p[6 * HID], p[7 * HID])};
  return __builtin_bit_cast(bfrag, q);
}

template<bool ZB>
__device__ __forceinline__ bfrag rd_slice(const char* sb, int lane) {
  if (ZB) {
    return *reinterpret_cast<const bfrag*>(sb + lane * 16);
  } else {
    float4 a = *reinterpret_cast<const float4*>(sb + lane * 16);
    float4 b = *reinterpret_cast<const float4*>(sb + 1024 + lane * 16);
    int4 q = {(int)cvtpk(a.x, a.y), (int)cvtpk(a.z, a.w),
              (int)cvtpk(b.x, b.y), (int)cvtpk(b.z, b.w)};
    return __builtin_bit_cast(bfrag, q);
  }
}

template<bool ZB>
__global__ __launch_bounds__(THREADS, 6) void fused_kernel(
    const float* __restrict__ zf, const unsigned short* __restrict__ z16,
    const int* __restrict__ ei, const float* __restrict__ ea,
    const float* __restrict__ W1, const float* __restrict__ b1,
    const float* __restrict__ W2, const float* __restrict__ b2,
    float* __restrict__ out)
{
  constexpr int SLB = ZB ? 1024 : 2048;   // bytes per k-slice (32 edges x 16 k)
  __shared__ __align__(16) char sl[2][8][SLB];   // [buf][slice][lane*16B]
  __shared__ float sp[2][4][BM];                 // cross-wave partials

  const int tid  = threadIdx.x;
  const int lane = tid & 63;
  const int wid  = tid >> 6;
  const int e    = lane & 31;        // edge within tile (= MFMA B col)
  const int hi   = lane >> 5;
  const int s0   = wid * 2;          // this wave stages slices s0, s0+1
  const int koff = (s0 & 3) * 16;    // k-offset within the node row
  const int T0   = blockIdx.x * TPB;
  const int* eiW = ei + (size_t)(wid >> 1) * EDGES;  // waves 0,1: src; 2,3: dst

  // ---- tile-invariant state (all straight-line SSA; no addressable arrays) ----
  const int wcol = wid * 32 + e;     // MFMA A row = hidden index
  bfrag Wf0 = load_wf(W1, 0 * 16 + hi * 8, wcol);
  bfrag Wf1 = load_wf(W1, 1 * 16 + hi * 8, wcol);
  bfrag Wf2 = load_wf(W1, 2 * 16 + hi * 8, wcol);
  bfrag Wf3 = load_wf(W1, 3 * 16 + hi * 8, wcol);
  bfrag Wf4 = load_wf(W1, 4 * 16 + hi * 8, wcol);
  bfrag Wf5 = load_wf(W1, 5 * 16 + hi * 8, wcol);
  bfrag Wf6 = load_wf(W1, 6 * 16 + hi * 8, wcol);
  bfrag Wf7 = load_wf(W1, 7 * 16 + hi * 8, wcol);
  bfrag Wf8 = load_wf(W1, 8 * 16 + hi * 8, wcol);

  // D layout (32x32): col = lane&31 (edge), row = (rg&3) + 8*(rg>>2) + 4*hi
  f16v b1v, w2v;
  #pragma unroll
  for (int rg = 0; rg < 16; ++rg) {
    int rh = (rg & 3) + 8 * (rg >> 2) + 4 * hi;
    b1v[rg] = b1[wid * 32 + rh];
    w2v[rg] = W2[wid * 32 + rh];
  }
  const float bias2 = b2[0];

  // ---- prologue: stage tile 0, prefetch ids(1),(2) and ea(0) ----
  {
    int n0 = eiW[(size_t)T0 * BM + e];
    if (ZB) {
      const unsigned short* g0 = z16 + (size_t)n0 * ZD + koff + hi * 8;
      gload16(g0,      &sl[0][s0][0]);
      gload16(g0 + 16, &sl[0][s0 + 1][0]);
    } else {
      const float* g0 = zf + (size_t)n0 * ZD + koff + hi * 8;
      gload16(g0,      &sl[0][s0][0]);
      gload16(g0 + 4,  &sl[0][s0][1024]);
      gload16(g0 + 16, &sl[0][s0 + 1][0]);
      gload16(g0 + 20, &sl[0][s0 + 1][1024]);
    }
  }
  int n1 = eiW[(size_t)(T0 + 1) * BM + e];
  int n2 = eiW[(size_t)(T0 + 2) * BM + e];
  const float* ep0 = ea + ((size_t)T0 * BM + e) * FD + hi * 8;
  float4 eA = *reinterpret_cast<const float4*>(ep0);
  float4 eB = *reinterpret_cast<const float4*>(ep0 + 4);

  for (int t = 0; t < TPB; ++t) {
    const int cur = t & 1, nxt = cur ^ 1;

    // b: drains stage(t) [vmcnt] and sp writes of t-1 [lgkmcnt]
    __syncthreads();

    // a: stage tile t+1 into sl[nxt] (flies until next barrier)
    {
      if (ZB) {
        const unsigned short* g0 = z16 + (size_t)n1 * ZD + koff + hi * 8;
        gload16(g0,      &sl[nxt][s0][0]);
        gload16(g0 + 16, &sl[nxt][s0 + 1][0]);
      } else {
        const float* g0 = zf + (size_t)n1 * ZD + koff + hi * 8;
        gload16(g0,      &sl[nxt][s0][0]);
        gload16(g0 + 4,  &sl[nxt][s0][1024]);
        gload16(g0 + 16, &sl[nxt][s0 + 1][0]);
        gload16(g0 + 20, &sl[nxt][s0 + 1][1024]);
      }
    }

    // c: wave 0 finishes tile t-1 (reduce partials, sigmoid, store)
    if (wid == 0 && t > 0 && lane < 32) {
      float s = sp[nxt][0][e] + sp[nxt][1][e] + sp[nxt][2][e] + sp[nxt][3][e] + bias2;
      out[(size_t)(T0 + t - 1) * BM + e] = 1.f / (1.f + __expf(-s));
    }

    // d: read this tile's 9 B-fragments
    const char* sb = &sl[cur][0][0];
    bfrag x0 = rd_slice<ZB>(sb + 0 * SLB, lane);
    bfrag x1 = rd_slice<ZB>(sb + 1 * SLB, lane);
    bfrag x2 = rd_slice<ZB>(sb + 2 * SLB, lane);
    bfrag x3 = rd_slice<ZB>(sb + 3 * SLB, lane);
    bfrag x4 = rd_slice<ZB>(sb + 4 * SLB, lane);
    bfrag x5 = rd_slice<ZB>(sb + 5 * SLB, lane);
    bfrag x6 = rd_slice<ZB>(sb + 6 * SLB, lane);
    bfrag x7 = rd_slice<ZB>(sb + 7 * SLB, lane);
    int4 eq = {(int)cvtpk(eA.x, eA.y), (int)cvtpk(eA.z, eA.w),
               (int)cvtpk(eB.x, eB.y), (int)cvtpk(eB.z, eB.w)};
    bfrag x8 = __builtin_bit_cast(bfrag, eq);

    // e: prefetch ids (2 ahead) and ea (1 ahead)
    n1 = n2;
    {
      int tl = (t + 3 < TPB) ? (t + 3) : (TPB - 1);
      n2 = eiW[(size_t)(T0 + tl) * BM + e];
      int te = (t + 1 < TPB) ? (t + 1) : (TPB - 1);
      const float* ep = ea + ((size_t)(T0 + te) * BM + e) * FD + hi * 8;
      eA = *reinterpret_cast<const float4*>(ep);
      eB = *reinterpret_cast<const float4*>(ep + 4);
    }

    // f: 9 MFMAs, bias1 folded into acc init
    f16v acc = b1v;
    acc = __builtin_amdgcn_mfma_f32_32x32x16_bf16(Wf0, x0, acc, 0, 0, 0);
    acc = __builtin_amdgcn_mfma_f32_32x32x16_bf16(Wf1, x1, acc, 0, 0, 0);
    acc = __builtin_amdgcn_mfma_f32_32x32x16_bf16(Wf2, x2, acc, 0, 0, 0);
    acc = __builtin_amdgcn_mfma_f32_32x32x16_bf16(Wf3, x3, acc, 0, 0, 0);
    acc = __builtin_amdgcn_mfma_f32_32x32x16_bf16(Wf4, x4, acc, 0, 0, 0);
    acc = __builtin_amdgcn_mfma_f32_32x32x16_bf16(Wf5, x5, acc, 0, 0, 0);
    acc = __builtin_amdgcn_mfma_f32_32x32x16_bf16(Wf6, x6, acc, 0, 0, 0);
    acc = __builtin_amdgcn_mfma_f32_32x32x16_bf16(Wf7, x7, acc, 0, 0, 0);
    acc = __builtin_amdgcn_mfma_f32_32x32x16_bf16(Wf8, x8, acc, 0, 0, 0);

    // g: ReLU + W2 dot in-register, fold lane halves, park partial in LDS
    float p = 0.f;
    #pragma unroll
    for (int rg = 0; rg < 16; ++rg)
      p = fmaf(fmaxf(acc[rg], 0.f), w2v[rg], p);
    p += __shfl_xor(p, 32);
    if (lane < 32) sp[cur][wid][e] = p;
  }

  // drain: finish last tile
  __syncthreads();
  if (wid == 0 && lane < 32) {
    float s = sp[(TPB - 1) & 1][0][e] + sp[(TPB - 1) & 1][1][e] +
              sp[(TPB - 1) & 1][2][e] + sp[(TPB - 1) & 1][3][e] + bias2;
    out[(size_t)(T0 + TPB - 1) * BM + e] = 1.f / (1.f + __expf(-s));
  }
}

extern "C" void kernel_launch(void* const* d_in, const int* in_sizes, int n_in,
                              void* d_out, int out_size, void* d_ws, size_t ws_size,
                              hipStream_t stream) {
  const float* z  = (const float*)d_in[0];
  const int*   ei = (const int*)d_in[1];
  const float* ea = (const float*)d_in[2];
  const float* W1 = (const float*)d_in[3];
  const float* b1 = (const float*)d_in[4];
  const float* W2 = (const float*)d_in[5];
  const float* b2 = (const float*)d_in[6];
  float* out = (float*)d_out;

  const size_t z16_bytes = (size_t)NN * ZD * sizeof(unsigned short);
  if (ws_size >= z16_bytes) {
    unsigned short* z16 = (unsigned short*)d_ws;
    const int n4 = NN * ZD / 4;
    zconv_kernel<<<(n4 + 255) / 256, 256, 0, stream>>>(z, z16, n4);
    fused_kernel<true><<<NBLK, THREADS, 0, stream>>>(z, z16, ei, ea, W1, b1, W2, b2, out);
  } else {
    fused_kernel<false><<<NBLK, THREADS, 0, stream>>>(z, nullptr, ei, ea, W1, b1, W2, b2, out);
  }
}

// Round 5
// 127.731 us; speedup vs baseline: 3.8164x; 3.8164x over previous
//
#include <hip/hip_runtime.h>

#define EDGES 1600000
#define NN    100000
#define ZD    64
#define FD    16
#define HID   128
#define BM    32         // edges per tile
#define THREADS 256
#define NBLK  2000       // 2000 blocks x 25 tiles x 32 edges = 1.6M exactly
#define TPB   25

typedef __attribute__((ext_vector_type(8)))  short bfrag;   // 8 bf16 = 4 VGPR
typedef __attribute__((ext_vector_type(16))) float f16v;    // 16 f32 acc

__device__ __forceinline__ unsigned short f2bf(float f) {
  unsigned u = __builtin_bit_cast(unsigned, f);
  u += 0x7fffu + ((u >> 16) & 1u);   // RNE
  return (unsigned short)(u >> 16);
}
__device__ __forceinline__ unsigned cvtpk(float lo, float hi) {
  unsigned r;
  asm("v_cvt_pk_bf16_f32 %0, %1, %2" : "=v"(r) : "v"(lo), "v"(hi));
  return r;
}
__device__ __forceinline__ void gload16(const void* g, void* l) {
  __builtin_amdgcn_global_load_lds(
      (const __attribute__((address_space(1))) unsigned int*)g,
      (__attribute__((address_space(3))) unsigned int*)l, 16, 0, 0);
}

__global__ void zconv_kernel(const float* __restrict__ z,
                             unsigned short* __restrict__ z16, int n4) {
  int i = blockIdx.x * blockDim.x + threadIdx.x;
  if (i >= n4) return;
  float4 f = reinterpret_cast<const float4*>(z)[i];
  ushort4 p;
  p.x = f2bf(f.x); p.y = f2bf(f.y); p.z = f2bf(f.z); p.w = f2bf(f.w);
  reinterpret_cast<ushort4*>(z16)[i] = p;
}

__device__ __forceinline__ bfrag load_wf(const float* __restrict__ W1, int k0, int wcol) {
  const float* p = W1 + (size_t)k0 * HID + wcol;
  int4 q = {(int)cvtpk(p[0],       p[HID]),
            (int)cvtpk(p[2 * HID], p[3 * HID]),
            (int)cvtpk(p[4 * HID], p[5 * HID]),
            (int)cvtpk(p[6 * HID], p[7 * HID])};
  return __builtin_bit_cast(bfrag, q);
}

template<bool ZB>
__device__ __forceinline__ bfrag rd_slice(const char* sb, int lane) {
  if (ZB) {
    return *reinterpret_cast<const bfrag*>(sb + lane * 16);
  } else {
    float4 a = *reinterpret_cast<const float4*>(sb + lane * 16);
    float4 b = *reinterpret_cast<const float4*>(sb + 1024 + lane * 16);
    int4 q = {(int)cvtpk(a.x, a.y), (int)cvtpk(a.z, a.w),
              (int)cvtpk(b.x, b.y), (int)cvtpk(b.z, b.w)};
    return __builtin_bit_cast(bfrag, q);
  }
}

template<bool ZB>
__global__ __launch_bounds__(THREADS, 2) void fused_kernel(
    const float* __restrict__ zf, const unsigned short* __restrict__ z16,
    const int* __restrict__ ei, const float* __restrict__ ea,
    const float* __restrict__ W1, const float* __restrict__ b1,
    const float* __restrict__ W2, const float* __restrict__ b2,
    float* __restrict__ out)
{
  constexpr int SLB = ZB ? 1024 : 2048;   // bytes per k-slice (32 edges x 16 k)
  __shared__ __align__(16) char sl[2][8][SLB];   // [buf][slice][lane*16B]
  __shared__ float sp[2][4][BM];                 // cross-wave partials

  const int tid  = threadIdx.x;
  const int lane = tid & 63;
  const int wid  = tid >> 6;
  const int e    = lane & 31;        // edge within tile (= MFMA B col)
  const int hi   = lane >> 5;
  const int s0   = wid * 2;          // this wave stages slices s0, s0+1
  const int koff = (s0 & 3) * 16;    // k-offset within the node row
  const int T0   = blockIdx.x * TPB;
  const int* eiW = ei + (size_t)(wid >> 1) * EDGES;  // waves 0,1: src; 2,3: dst

  // ---- tile-invariant state (all straight-line SSA; no addressable arrays) ----
  const int wcol = wid * 32 + e;     // MFMA A row = hidden index
  bfrag Wf0 = load_wf(W1, 0 * 16 + hi * 8, wcol);
  bfrag Wf1 = load_wf(W1, 1 * 16 + hi * 8, wcol);
  bfrag Wf2 = load_wf(W1, 2 * 16 + hi * 8, wcol);
  bfrag Wf3 = load_wf(W1, 3 * 16 + hi * 8, wcol);
  bfrag Wf4 = load_wf(W1, 4 * 16 + hi * 8, wcol);
  bfrag Wf5 = load_wf(W1, 5 * 16 + hi * 8, wcol);
  bfrag Wf6 = load_wf(W1, 6 * 16 + hi * 8, wcol);
  bfrag Wf7 = load_wf(W1, 7 * 16 + hi * 8, wcol);
  bfrag Wf8 = load_wf(W1, 8 * 16 + hi * 8, wcol);

  // D layout (32x32): col = lane&31 (edge), row = (rg&3) + 8*(rg>>2) + 4*hi
  f16v b1v, w2v;
  #pragma unroll
  for (int rg = 0; rg < 16; ++rg) {
    int rh = (rg & 3) + 8 * (rg >> 2) + 4 * hi;
    b1v[rg] = b1[wid * 32 + rh];
    w2v[rg] = W2[wid * 32 + rh];
  }
  const float bias2 = b2[0];

  // ---- prologue: stage tile 0, prefetch ids(1),(2) and ea(0) ----
  {
    int n0 = eiW[(size_t)T0 * BM + e];
    if (ZB) {
      const unsigned short* g0 = z16 + (size_t)n0 * ZD + koff + hi * 8;
      gload16(g0,      &sl[0][s0][0]);
      gload16(g0 + 16, &sl[0][s0 + 1][0]);
    } else {
      const float* g0 = zf + (size_t)n0 * ZD + koff + hi * 8;
      gload16(g0,      &sl[0][s0][0]);
      gload16(g0 + 4,  &sl[0][s0][1024]);
      gload16(g0 + 16, &sl[0][s0 + 1][0]);
      gload16(g0 + 20, &sl[0][s0 + 1][1024]);
    }
  }
  int n1 = eiW[(size_t)(T0 + 1) * BM + e];
  int n2 = eiW[(size_t)(T0 + 2) * BM + e];
  const float* ep0 = ea + ((size_t)T0 * BM + e) * FD + hi * 8;
  float4 eA = *reinterpret_cast<const float4*>(ep0);
  float4 eB = *reinterpret_cast<const float4*>(ep0 + 4);

  for (int t = 0; t < TPB; ++t) {
    const int cur = t & 1, nxt = cur ^ 1;

    // b: drains stage(t) [vmcnt] and sp writes of t-1 [lgkmcnt]
    __syncthreads();

    // a: stage tile t+1 into sl[nxt] (flies until next barrier)
    {
      if (ZB) {
        const unsigned short* g0 = z16 + (size_t)n1 * ZD + koff + hi * 8;
        gload16(g0,      &sl[nxt][s0][0]);
        gload16(g0 + 16, &sl[nxt][s0 + 1][0]);
      } else {
        const float* g0 = zf + (size_t)n1 * ZD + koff + hi * 8;
        gload16(g0,      &sl[nxt][s0][0]);
        gload16(g0 + 4,  &sl[nxt][s0][1024]);
        gload16(g0 + 16, &sl[nxt][s0 + 1][0]);
        gload16(g0 + 20, &sl[nxt][s0 + 1][1024]);
      }
    }

    // c: wave 0 finishes tile t-1 (reduce partials, sigmoid, store)
    if (wid == 0 && t > 0 && lane < 32) {
      float s = sp[nxt][0][e] + sp[nxt][1][e] + sp[nxt][2][e] + sp[nxt][3][e] + bias2;
      out[(size_t)(T0 + t - 1) * BM + e] = 1.f / (1.f + __expf(-s));
    }

    // d: read this tile's 9 B-fragments
    const char* sb = &sl[cur][0][0];
    bfrag x0 = rd_slice<ZB>(sb + 0 * SLB, lane);
    bfrag x1 = rd_slice<ZB>(sb + 1 * SLB, lane);
    bfrag x2 = rd_slice<ZB>(sb + 2 * SLB, lane);
    bfrag x3 = rd_slice<ZB>(sb + 3 * SLB, lane);
    bfrag x4 = rd_slice<ZB>(sb + 4 * SLB, lane);
    bfrag x5 = rd_slice<ZB>(sb + 5 * SLB, lane);
    bfrag x6 = rd_slice<ZB>(sb + 6 * SLB, lane);
    bfrag x7 = rd_slice<ZB>(sb + 7 * SLB, lane);
    int4 eq = {(int)cvtpk(eA.x, eA.y), (int)cvtpk(eA.z, eA.w),
               (int)cvtpk(eB.x, eB.y), (int)cvtpk(eB.z, eB.w)};
    bfrag x8 = __builtin_bit_cast(bfrag, eq);

    // e: prefetch ids (2 ahead) and ea (1 ahead)
    n1 = n2;
    {
      int tl = (t + 3 < TPB) ? (t + 3) : (TPB - 1);
      n2 = eiW[(size_t)(T0 + tl) * BM + e];
      int te = (t + 1 < TPB) ? (t + 1) : (TPB - 1);
      const float* ep = ea + ((size_t)(T0 + te) * BM + e) * FD + hi * 8;
      eA = *reinterpret_cast<const float4*>(ep);
      eB = *reinterpret_cast<const float4*>(ep + 4);
    }

    // f: 9 MFMAs, bias1 folded into acc init
    f16v acc = b1v;
    acc = __builtin_amdgcn_mfma_f32_32x32x16_bf16(Wf0, x0, acc, 0, 0, 0);
    acc = __builtin_amdgcn_mfma_f32_32x32x16_bf16(Wf1, x1, acc, 0, 0, 0);
    acc = __builtin_amdgcn_mfma_f32_32x32x16_bf16(Wf2, x2, acc, 0, 0, 0);
    acc = __builtin_amdgcn_mfma_f32_32x32x16_bf16(Wf3, x3, acc, 0, 0, 0);
    acc = __builtin_amdgcn_mfma_f32_32x32x16_bf16(Wf4, x4, acc, 0, 0, 0);
    acc = __builtin_amdgcn_mfma_f32_32x32x16_bf16(Wf5, x5, acc, 0, 0, 0);
    acc = __builtin_amdgcn_mfma_f32_32x32x16_bf16(Wf6, x6, acc, 0, 0, 0);
    acc = __builtin_amdgcn_mfma_f32_32x32x16_bf16(Wf7, x7, acc, 0, 0, 0);
    acc = __builtin_amdgcn_mfma_f32_32x32x16_bf16(Wf8, x8, acc, 0, 0, 0);

    // g: ReLU + W2 dot in-register, fold lane halves, park partial in LDS
    float p = 0.f;
    #pragma unroll
    for (int rg = 0; rg < 16; ++rg)
      p = fmaf(fmaxf(acc[rg], 0.f), w2v[rg], p);
    p += __shfl_xor(p, 32);
    if (lane < 32) sp[cur][wid][e] = p;
  }

  // drain: finish last tile
  __syncthreads();
  if (wid == 0 && lane < 32) {
    float s = sp[(TPB - 1) & 1][0][e] + sp[(TPB - 1) & 1][1][e] +
              sp[(TPB - 1) & 1][2][e] + sp[(TPB - 1) & 1][3][e] + bias2;
    out[(size_t)(T0 + TPB - 1) * BM + e] = 1.f / (1.f + __expf(-s));
  }
}

extern "C" void kernel_launch(void* const* d_in, const int* in_sizes, int n_in,
                              void* d_out, int out_size, void* d_ws, size_t ws_size,
                              hipStream_t stream) {
  const float* z  = (const float*)d_in[0];
  const int*   ei = (const int*)d_in[1];
  const float* ea = (const float*)d_in[2];
  const float* W1 = (const float*)d_in[3];
  const float* b1 = (const float*)d_in[4];
  const float* W2 = (const float*)d_in[5];
  const float* b2 = (const float*)d_in[6];
  float* out = (float*)d_out;

  const size_t z16_bytes = (size_t)NN * ZD * sizeof(unsigned short);
  if (ws_size >= z16_bytes) {
    unsigned short* z16 = (unsigned short*)d_ws;
    const int n4 = NN * ZD / 4;
    zconv_kernel<<<(n4 + 255) / 256, 256, 0, stream>>>(z, z16, n4);
    fused_kernel<true><<<NBLK, THREADS, 0, stream>>>(z, z16, ei, ea, W1, b1, W2, b2, out);
  } else {
    fused_kernel<false><<<NBLK, THREADS, 0, stream>>>(z, nullptr, ei, ea, W1, b1, W2, b2, out);
  }
}